// Round 5
// baseline (278.889 us; speedup 1.0000x reference)
//
#include <hip/hip_runtime.h>

// asymmetricLoss: out = mean(w * |x - y|), w = 0.7 if x<y else 0.3
// x,y: fp32, shape (32,1,1024,1024) -> N = 33,554,432 elements.
// Memory-bound reduction: 256 MiB read total.

#define N_TOTAL 33554432
#define NBLOCKS 2048
#define NTHREADS 256

__global__ __launch_bounds__(NTHREADS) void
asym_partial_kernel(const float4* __restrict__ x,
                    const float4* __restrict__ y,
                    float* __restrict__ partials,
                    int n4) {
    int tid = blockIdx.x * blockDim.x + threadIdx.x;
    int stride = gridDim.x * blockDim.x;
    float acc = 0.0f;
    for (int i = tid; i < n4; i += stride) {
        float4 xv = x[i];
        float4 yv = y[i];
        float d0 = xv.x - yv.x;
        float d1 = xv.y - yv.y;
        float d2 = xv.z - yv.z;
        float d3 = xv.w - yv.w;
        // w*|d| with w = 0.7 if d<0 else 0.3  ==  max(0.3*d, -0.7*d)
        acc += fmaxf(0.3f * d0, -0.7f * d0);
        acc += fmaxf(0.3f * d1, -0.7f * d1);
        acc += fmaxf(0.3f * d2, -0.7f * d2);
        acc += fmaxf(0.3f * d3, -0.7f * d3);
    }
    // wave (64-lane) shuffle reduce
    #pragma unroll
    for (int off = 32; off > 0; off >>= 1)
        acc += __shfl_down(acc, off, 64);
    __shared__ float lds[NTHREADS / 64];
    int lane = threadIdx.x & 63;
    int wave = threadIdx.x >> 6;
    if (lane == 0) lds[wave] = acc;
    __syncthreads();
    if (threadIdx.x == 0) {
        float s = 0.0f;
        #pragma unroll
        for (int w = 0; w < NTHREADS / 64; ++w) s += lds[w];
        partials[blockIdx.x] = s;
    }
}

__global__ __launch_bounds__(NTHREADS) void
asym_final_kernel(const float* __restrict__ partials,
                  int nblocks,
                  float* __restrict__ out) {
    float acc = 0.0f;
    for (int i = threadIdx.x; i < nblocks; i += NTHREADS) acc += partials[i];
    #pragma unroll
    for (int off = 32; off > 0; off >>= 1)
        acc += __shfl_down(acc, off, 64);
    __shared__ float lds[NTHREADS / 64];
    int lane = threadIdx.x & 63;
    int wave = threadIdx.x >> 6;
    if (lane == 0) lds[wave] = acc;
    __syncthreads();
    if (threadIdx.x == 0) {
        float s = 0.0f;
        #pragma unroll
        for (int w = 0; w < NTHREADS / 64; ++w) s += lds[w];
        out[0] = s * (1.0f / (float)N_TOTAL);
    }
}

extern "C" void kernel_launch(void* const* d_in, const int* in_sizes, int n_in,
                              void* d_out, int out_size, void* d_ws, size_t ws_size,
                              hipStream_t stream) {
    const float4* x = (const float4*)d_in[0];
    const float4* y = (const float4*)d_in[1];
    float* partials = (float*)d_ws;   // NBLOCKS floats = 8 KB
    float* out = (float*)d_out;

    int n4 = N_TOTAL / 4;  // 8,388,608 float4 pairs

    asym_partial_kernel<<<NBLOCKS, NTHREADS, 0, stream>>>(x, y, partials, n4);
    asym_final_kernel<<<1, NTHREADS, 0, stream>>>(partials, NBLOCKS, out);
}

// Round 6
// 274.244 us; speedup vs baseline: 1.0169x; 1.0169x over previous
//
#include <hip/hip_runtime.h>

// asymmetricLoss: out = mean(w * |x - y|), w = 0.7 if x<y else 0.3
// x,y: fp32, shape (32,1,1024,1024) -> N = 33,554,432 elements.
// Memory-bound reduction: 256 MiB read total.
//
// R5 post-mortem: VGPR_Count=12 -> compiler serialized the 2 loads per
// iteration, latency-exposed at 2.6 TB/s effective. Fix: compile-time trip
// count + full unroll + 4 accumulators -> many dwordx4 loads in flight.

#define N_TOTAL 33554432
#define N4      (N_TOTAL / 4)     // 8,388,608 float4 pairs
#define NBLOCKS 2048
#define NTHREADS 256
#define STRIDE  (NBLOCKS * NTHREADS)          // 524,288 threads
#define PER_THREAD (N4 / STRIDE)              // 16 float4 iterations, exact

__global__ __launch_bounds__(NTHREADS) void
asym_partial_kernel(const float4* __restrict__ x,
                    const float4* __restrict__ y,
                    float* __restrict__ partials) {
    const int tid = blockIdx.x * NTHREADS + threadIdx.x;

    float acc0 = 0.0f, acc1 = 0.0f, acc2 = 0.0f, acc3 = 0.0f;

    // Fully unrolled: compiler can hoist/batch loads (high vmcnt depth).
    #pragma unroll
    for (int k = 0; k < PER_THREAD; ++k) {
        const int i = tid + k * STRIDE;
        float4 xv = x[i];
        float4 yv = y[i];
        float d0 = xv.x - yv.x;
        float d1 = xv.y - yv.y;
        float d2 = xv.z - yv.z;
        float d3 = xv.w - yv.w;
        // w*|d| with w = 0.7 if d<0 else 0.3  ==  max(0.3*d, -0.7*d)
        acc0 += fmaxf(0.3f * d0, -0.7f * d0);
        acc1 += fmaxf(0.3f * d1, -0.7f * d1);
        acc2 += fmaxf(0.3f * d2, -0.7f * d2);
        acc3 += fmaxf(0.3f * d3, -0.7f * d3);
    }
    float acc = (acc0 + acc1) + (acc2 + acc3);

    // wave (64-lane) shuffle reduce
    #pragma unroll
    for (int off = 32; off > 0; off >>= 1)
        acc += __shfl_down(acc, off, 64);
    __shared__ float lds[NTHREADS / 64];
    int lane = threadIdx.x & 63;
    int wave = threadIdx.x >> 6;
    if (lane == 0) lds[wave] = acc;
    __syncthreads();
    if (threadIdx.x == 0) {
        float s = 0.0f;
        #pragma unroll
        for (int w = 0; w < NTHREADS / 64; ++w) s += lds[w];
        partials[blockIdx.x] = s;
    }
}

__global__ __launch_bounds__(NTHREADS) void
asym_final_kernel(const float* __restrict__ partials,
                  float* __restrict__ out) {
    float acc = 0.0f;
    for (int i = threadIdx.x; i < NBLOCKS; i += NTHREADS) acc += partials[i];
    #pragma unroll
    for (int off = 32; off > 0; off >>= 1)
        acc += __shfl_down(acc, off, 64);
    __shared__ float lds[NTHREADS / 64];
    int lane = threadIdx.x & 63;
    int wave = threadIdx.x >> 6;
    if (lane == 0) lds[wave] = acc;
    __syncthreads();
    if (threadIdx.x == 0) {
        float s = 0.0f;
        #pragma unroll
        for (int w = 0; w < NTHREADS / 64; ++w) s += lds[w];
        out[0] = s * (1.0f / (float)N_TOTAL);
    }
}

extern "C" void kernel_launch(void* const* d_in, const int* in_sizes, int n_in,
                              void* d_out, int out_size, void* d_ws, size_t ws_size,
                              hipStream_t stream) {
    const float4* x = (const float4*)d_in[0];
    const float4* y = (const float4*)d_in[1];
    float* partials = (float*)d_ws;   // NBLOCKS floats = 8 KB
    float* out = (float*)d_out;

    asym_partial_kernel<<<NBLOCKS, NTHREADS, 0, stream>>>(x, y, partials);
    asym_final_kernel<<<1, NTHREADS, 0, stream>>>(partials, out);
}